// Round 6
// baseline (904.475 us; speedup 1.0000x reference)
//
#include <hip/hip_runtime.h>
#include <hip/hip_bf16.h>

#define NB 262144
#define ZD 510
#define NK 128
#define GAP_THR 1.0f
#define CHUNK 64
#define NCHUNK 8

typedef _Float16 half8 __attribute__((ext_vector_type(8)));
typedef __attribute__((ext_vector_type(16))) float f32x16;

// ws layout (bytes): [0,512) csq | [4096, 4096+131072) cb16 pre-swizzled | [139264, +1MB) kf
#define WS_CB16_OFF 4096
#define WS_KF_OFF   139264

// --- K0: csq[k] = ||cb[k]||^2 (fp64) + pre-split/pre-swizzle cb -> fp16 ws ---
// 128 blocks (one per code) x 256 threads.
__global__ void prep_kernel(const float* __restrict__ cb, float* __restrict__ csq,
                            ushort* __restrict__ cb16) {
    const int code = blockIdx.x;
    const int tid  = threadIdx.x;
    const float* row = cb + (size_t)code * ZD;

    // csq in fp64 (identical math to verified round-5 csq: per-lane fp64 fma + reduce)
    __shared__ double ws_red[4];
    double s = 0.0;
    for (int j = 0; j < 2; ++j) {
        int d = tid + (j << 8);
        if (d < ZD) { double v = (double)row[d]; s = fma(v, v, s); }
    }
#pragma unroll
    for (int m = 1; m <= 32; m <<= 1) s += __shfl_xor(s, m, 64);
    if ((tid & 63) == 0) ws_red[tid >> 6] = s;
    __syncthreads();
    if (tid == 0) csq[code] = (float)(ws_red[0] + ws_red[1] + ws_red[2] + ws_red[3]);

    // cb16: ws[c*8192 + code*64 + j*8 + e] = fp16(cb[code][c*64 + ((j^(code&7))<<3) + e])
    const int sw = code & 7;
#pragma unroll
    for (int u = 0; u < 2; ++u) {
        int o = tid + (u << 8);                 // 0..511 output slot
        int c = o >> 6, j = (o >> 3) & 7, e = o & 7;
        int src_d = (c << 6) | ((j ^ sw) << 3) | e;
        float v = (src_d < ZD) ? row[src_d] : 0.f;
        cb16[(c << 13) + (code << 6) + ((o & 63))] = (ushort)__builtin_bit_cast(short, (_Float16)v);
    }
}

// --- K1: fp16 MFMA scores + argmin + gap flag + gather write ---
// 256 thr = 4 waves; wave w owns 32 rows. cb double-buffered in LDS from pre-swizzled ws.
__global__ __launch_bounds__(256, 3) void vq_fused(
    const float* __restrict__ z, const float* __restrict__ cb,
    const uint4* __restrict__ cb16, const float* __restrict__ csq,
    int* __restrict__ kf, float* __restrict__ out) {
    __shared__ __align__(16) ushort buf[2][NK * CHUNK];   // 2 x 16 KB
    __shared__ int km[128];

    const int tid   = threadIdx.x;
    const int lane  = tid & 63;
    const int wv    = tid >> 6;
    const int cmod  = lane & 31;
    const int hi    = lane >> 5;
    const int brow0 = blockIdx.x << 7;
    const int wrow0 = brow0 + (wv << 5);

    f32x16 acc[4];
#pragma unroll
    for (int cf = 0; cf < 4; ++cf)
#pragma unroll
        for (int e = 0; e < 16; ++e) acc[cf][e] = 0.f;

    const float* zrow = z + (size_t)(wrow0 + cmod) * ZD;

    // prologue: stage chunk 0 (linear copy of pre-swizzled block; strided units -> conflict-free b128)
    {
        uint4 st[4];
#pragma unroll
        for (int i = 0; i < 4; ++i) st[i] = cb16[i * 256 + tid];
#pragma unroll
        for (int i = 0; i < 4; ++i) ((uint4*)buf[0])[i * 256 + tid] = st[i];
    }
    int cur = 0;

    for (int c = 0; c < NCHUNK; ++c) {
        uint4 nxt[4];
        if (c < NCHUNK - 1) {
#pragma unroll
            for (int i = 0; i < 4; ++i) nxt[i] = cb16[(c + 1) * 1024 + i * 256 + tid];
        }
        __syncthreads();                        // buf[cur] ready for all waves

        // hoist all 16 z float2 loads for this chunk
        const int c0 = c * CHUNK;
        float2 zr2[16];
#pragma unroll
        for (int t = 0; t < 4; ++t) {
            const int dbase = c0 + (t << 4) + (hi << 3);
            zr2[t * 4 + 0] = *(const float2*)(zrow + dbase);
            zr2[t * 4 + 1] = *(const float2*)(zrow + dbase + 2);
            zr2[t * 4 + 2] = *(const float2*)(zrow + dbase + 4);
            zr2[t * 4 + 3] = (dbase + 6 < ZD) ? *(const float2*)(zrow + dbase + 6)
                                              : make_float2(0.f, 0.f);
        }

#pragma unroll
        for (int t = 0; t < 4; ++t) {
            half8 a;
            a[0] = (_Float16)zr2[t * 4 + 0].x; a[1] = (_Float16)zr2[t * 4 + 0].y;
            a[2] = (_Float16)zr2[t * 4 + 1].x; a[3] = (_Float16)zr2[t * 4 + 1].y;
            a[4] = (_Float16)zr2[t * 4 + 2].x; a[5] = (_Float16)zr2[t * 4 + 2].y;
            a[6] = (_Float16)zr2[t * 4 + 3].x; a[7] = (_Float16)zr2[t * 4 + 3].y;

            const int sc = (t << 1) | hi;
            const int ba = cmod * CHUNK + ((sc ^ (cmod & 7)) << 3);
#pragma unroll
            for (int cf = 0; cf < 4; ++cf) {
                half8 b = *(const half8*)&buf[cur][(cf << 11) + ba];
                acc[cf] = __builtin_amdgcn_mfma_f32_32x32x16_f16(a, b, acc[cf], 0, 0, 0);
            }
        }

        if (c < NCHUNK - 1) {
#pragma unroll
            for (int i = 0; i < 4; ++i) ((uint4*)buf[cur ^ 1])[i * 256 + tid] = nxt[i];
            cur ^= 1;
        }
    }

    // epilogue: score = csq - 2*cross; min1/min2 + argmin per row (identical logic)
    float cq[4];
#pragma unroll
    for (int cf = 0; cf < 4; ++cf) cq[cf] = csq[cf * 32 + cmod];

#pragma unroll
    for (int reg = 0; reg < 16; ++reg) {
        float bv = fmaf(-2.f, acc[0][reg], cq[0]);
        int   bk = cmod;
        float m2 = 1e30f;
#pragma unroll
        for (int cf = 1; cf < 4; ++cf) {
            float v = fmaf(-2.f, acc[cf][reg], cq[cf]);
            int  kk = cf * 32 + cmod;
            if (v < bv)      { m2 = bv; bv = v; bk = kk; }
            else if (v < m2) { m2 = v; }
        }
#pragma unroll
        for (int m = 1; m <= 16; m <<= 1) {
            float ov  = __shfl_xor(bv, m, 64);
            int   ok  = __shfl_xor(bk, m, 64);
            float om2 = __shfl_xor(m2, m, 64);
            float nm2 = fminf(fmaxf(bv, ov), fminf(m2, om2));
            bool take = (ov < bv) || (ov == bv && ok < bk);
            bv = take ? ov : bv;
            bk = take ? ok : bk;
            m2 = nm2;
        }
        if (cmod == 0) {
            int rloc = (reg & 3) + ((reg >> 2) << 3) + (hi << 2);
            int enc  = bk;
            if (m2 - bv < GAP_THR) enc |= (int)0x80000000;
            km[(wv << 5) + rloc] = enc;
            kf[wrow0 + rloc] = enc;
        }
    }
    __syncthreads();

    // gather write: 2 rows/pass, 128 threads/row, float2
    const int half = tid >> 7, h = tid & 127;
    for (int rp = 0; rp < 64; ++rp) {
        int row = (rp << 1) + half;
        int k   = km[row] & 127;
        const float2* src = (const float2*)(cb + (size_t)k * ZD);
        float2*       dst = (float2*)(out + (size_t)(brow0 + row) * ZD);
        dst[h] = src[h];
        if (h < 127) dst[128 + h] = src[128 + h];
    }
}

// --- K2: exact fp32 re-score of flagged rows (math byte-identical to verified round-5) ---
__global__ __launch_bounds__(256) void repair(
    const float* __restrict__ z, const float* __restrict__ cb,
    const float* __restrict__ csq, const int* __restrict__ kf,
    float* __restrict__ out) {
    __shared__ float zs[512];
    __shared__ int   kmrow[128];
    __shared__ float wm[2];
    __shared__ int   wk[2];
    __shared__ int   kwin;
    const int tid  = threadIdx.x;
    const int row0 = blockIdx.x << 7;
    if (tid < 128) kmrow[tid] = kf[row0 + tid];
    __syncthreads();
    // fast exit for blocks with no flagged rows
    int nflag = __syncthreads_count(tid < 128 && kmrow[tid] < 0);
    if (nflag == 0) return;

    for (int rl = 0; rl < 128; ++rl) {
        if (kmrow[rl] >= 0) continue;                  // uniform skip
        int row = row0 + rl;
        for (int j = tid; j < 512; j += 256) zs[j] = (j < ZD) ? z[(size_t)row * ZD + j] : 0.f;
        __syncthreads();
        float sc = 1e30f;
        if (tid < NK) {
            const float* cr = cb + (size_t)tid * ZD;
            float s = 0.f;
#pragma unroll 6
            for (int d = 0; d < ZD; ++d) s = fmaf(zs[d], cr[d], s);
            sc = fmaf(-2.f, s, csq[tid]);
        }
        if (tid < 128) {
            float bv = sc; int bk = tid;
#pragma unroll
            for (int m = 1; m <= 32; m <<= 1) {
                float ov = __shfl_xor(bv, m, 64);
                int   ok = __shfl_xor(bk, m, 64);
                bool take = (ov < bv) || (ov == bv && ok < bk);
                bv = take ? ov : bv;
                bk = take ? ok : bk;
            }
            if ((tid & 63) == 0) { wm[tid >> 6] = bv; wk[tid >> 6] = bk; }
        }
        __syncthreads();
        if (tid == 0) {
            bool t1 = (wm[1] < wm[0]) || (wm[1] == wm[0] && wk[1] < wk[0]);
            kwin = t1 ? wk[1] : wk[0];
        }
        __syncthreads();
        int k = kwin;
        const float2* src = (const float2*)(cb + (size_t)k * ZD);
        float2*       dst = (float2*)(out + (size_t)row * ZD);
        if (tid < 255) dst[tid] = src[tid];
        __syncthreads();
    }
}

extern "C" void kernel_launch(void* const* d_in, const int* in_sizes, int n_in,
                              void* d_out, int out_size, void* d_ws, size_t ws_size,
                              hipStream_t stream) {
    const float* z  = (const float*)d_in[0];
    const float* cb = (const float*)d_in[1];
    float*  out  = (float*)d_out;
    float*  csq  = (float*)d_ws;
    ushort* cb16 = (ushort*)((char*)d_ws + WS_CB16_OFF);
    int*    kf   = (int*)((char*)d_ws + WS_KF_OFF);

    prep_kernel<<<NK, 256, 0, stream>>>(cb, csq, cb16);
    vq_fused<<<NB / 128, 256, 0, stream>>>(z, cb, (const uint4*)cb16, csq, kf, out);
    repair<<<NB / 128, 256, 0, stream>>>(z, cb, csq, kf, out);
}

// Round 7
// 722.441 us; speedup vs baseline: 1.2520x; 1.2520x over previous
//
#include <hip/hip_runtime.h>

#define NB 262144
#define ZD 510
#define NK 128
#define GAP_THR 0.5f
#define CHW 68                    // padded row stride in ushorts (136 B)
#define CHUNK_USH (NK * CHW)      // 8704 ushorts = 17408 B per chunk image
#define CHUNK_U4  (CHUNK_USH / 8) // 1088 uint4

typedef _Float16 half8 __attribute__((ext_vector_type(8)));
typedef __attribute__((ext_vector_type(16))) float f32x16;

// ws layout: [0,512) csq | [512, 512+139264) cb16 padded fp16 image | kf after
#define WS_CB16_OFF 512
#define WS_KF_OFF   139776

__device__ inline ushort f2h(float v) {
    return (ushort)__builtin_bit_cast(short, (_Float16)v);
}

// --- K0: csq (fp64, verified math) + padded fp16 cb image ---
__global__ void prep_kernel(const float* __restrict__ cb, float* __restrict__ csq,
                            ushort* __restrict__ cb16) {
    const int code = blockIdx.x;
    const int tid  = threadIdx.x;
    const float* row = cb + (size_t)code * ZD;

    __shared__ double ws_red[4];
    double s = 0.0;
    for (int j = 0; j < 2; ++j) {
        int d = tid + (j << 8);
        if (d < ZD) { double v = (double)row[d]; s = fma(v, v, s); }
    }
#pragma unroll
    for (int m = 1; m <= 32; m <<= 1) s += __shfl_xor(s, m, 64);
    if ((tid & 63) == 0) ws_red[tid >> 6] = s;
    __syncthreads();
    if (tid == 0) csq[code] = (float)(ws_red[0] + ws_red[1] + ws_red[2] + ws_red[3]);

    // image: cb16[ch*8704 + code*68 + off] = fp16(cb[code][ch*64+off]), pad off>=64 & d>=510 -> 0
    for (int s2 = tid; s2 < 8 * CHW; s2 += 256) {
        int ch = s2 / CHW, off = s2 - ch * CHW;
        int d  = (ch << 6) + off;
        float v = (off < 64 && d < ZD) ? row[d] : 0.f;
        cb16[ch * CHUNK_USH + code * CHW + off] = f2h(v);
    }
}

// --- K1: fp16 MFMA + argmin + flag + gather; z AND cb staged via LDS ---
__global__ __launch_bounds__(256, 2) void vq_fused(
    const float* __restrict__ z, const float* __restrict__ cb,
    const uint4* __restrict__ cb16, const float* __restrict__ csq,
    int* __restrict__ kf, float* __restrict__ out) {
    __shared__ __align__(16) ushort zb[2][CHUNK_USH];    // 2 x 17408 B
    __shared__ __align__(16) ushort cbb[2][CHUNK_USH];   // 2 x 17408 B
    __shared__ int km[128];

    const int tid   = threadIdx.x;
    const int lane  = tid & 63;
    const int wv    = tid >> 6;
    const int cmod  = lane & 31;
    const int hi    = lane >> 5;
    const int brow0 = blockIdx.x << 7;
    const int wrow0 = brow0 + (wv << 5);

    const int srow = tid >> 5;              // staging: 8 rows per pass
    const int d0   = (tid & 31) << 1;       // even d within chunk

    f32x16 acc[4];
#pragma unroll
    for (int cf = 0; cf < 4; ++cf)
#pragma unroll
        for (int e = 0; e < 16; ++e) acc[cf][e] = 0.f;

    float2 zr[16];
    uint4  cr[5];

    // ---- stage chunk 0 ----
#pragma unroll
    for (int p = 0; p < 16; ++p) {
        int r = (p << 3) + srow;
        zr[p] = (d0 < 509) ? *(const float2*)(z + (size_t)(brow0 + r) * ZD + d0)
                           : make_float2(0.f, 0.f);
    }
#pragma unroll
    for (int i = 0; i < 4; ++i) cr[i] = cb16[(i << 8) + tid];
    if (tid < 64) cr[4] = cb16[1024 + tid];
#pragma unroll
    for (int p = 0; p < 16; ++p) {
        int r = (p << 3) + srow;
        *(uint*)&zb[0][r * CHW + d0] = (uint)f2h(zr[p].x) | ((uint)f2h(zr[p].y) << 16);
    }
#pragma unroll
    for (int i = 0; i < 4; ++i) ((uint4*)cbb[0])[(i << 8) + tid] = cr[i];
    if (tid < 64) ((uint4*)cbb[0])[1024 + tid] = cr[4];

    int cur = 0;
    for (int c = 0; c < 8; ++c) {
        // issue next-chunk global loads (hide under compute)
        if (c < 7) {
            const int cg = (c + 1) << 6;
#pragma unroll
            for (int p = 0; p < 16; ++p) {
                int r = (p << 3) + srow;
                int dg = cg + d0;
                zr[p] = (dg < 509) ? *(const float2*)(z + (size_t)(brow0 + r) * ZD + dg)
                                   : make_float2(0.f, 0.f);
            }
#pragma unroll
            for (int i = 0; i < 4; ++i) cr[i] = cb16[(c + 1) * CHUNK_U4 + (i << 8) + tid];
            if (tid < 64) cr[4] = cb16[(c + 1) * CHUNK_U4 + 1024 + tid];
        }

        __syncthreads();   // buf[cur] writes visible; prior reads of buf[cur^1] done

        // ---- compute on buf[cur] ----
        const int abase = (wv * 32 + cmod) * CHW + (hi << 3);
#pragma unroll
        for (int t = 0; t < 4; ++t) {
            union { uint2 u2[2]; half8 h; } a;
            a.u2[0] = *(const uint2*)&zb[cur][abase + (t << 4)];
            a.u2[1] = *(const uint2*)&zb[cur][abase + (t << 4) + 4];
#pragma unroll
            for (int cf = 0; cf < 4; ++cf) {
                const int bbase = (cf * 32 + cmod) * CHW + (t << 4) + (hi << 3);
                union { uint2 u2[2]; half8 h; } b;
                b.u2[0] = *(const uint2*)&cbb[cur][bbase];
                b.u2[1] = *(const uint2*)&cbb[cur][bbase + 4];
                acc[cf] = __builtin_amdgcn_mfma_f32_32x32x16_f16(a.h, b.h, acc[cf], 0, 0, 0);
            }
        }

        // ---- write next chunk into other buffer ----
        if (c < 7) {
#pragma unroll
            for (int p = 0; p < 16; ++p) {
                int r = (p << 3) + srow;
                *(uint*)&zb[cur ^ 1][r * CHW + d0] =
                    (uint)f2h(zr[p].x) | ((uint)f2h(zr[p].y) << 16);
            }
#pragma unroll
            for (int i = 0; i < 4; ++i) ((uint4*)cbb[cur ^ 1])[(i << 8) + tid] = cr[i];
            if (tid < 64) ((uint4*)cbb[cur ^ 1])[1024 + tid] = cr[4];
            cur ^= 1;
        }
    }

    // ---- epilogue (byte-identical logic to verified rounds) ----
    float cq[4];
#pragma unroll
    for (int cf = 0; cf < 4; ++cf) cq[cf] = csq[cf * 32 + cmod];

#pragma unroll
    for (int reg = 0; reg < 16; ++reg) {
        float bv = fmaf(-2.f, acc[0][reg], cq[0]);
        int   bk = cmod;
        float m2 = 1e30f;
#pragma unroll
        for (int cf = 1; cf < 4; ++cf) {
            float v = fmaf(-2.f, acc[cf][reg], cq[cf]);
            int  kk = cf * 32 + cmod;
            if (v < bv)      { m2 = bv; bv = v; bk = kk; }
            else if (v < m2) { m2 = v; }
        }
#pragma unroll
        for (int m = 1; m <= 16; m <<= 1) {
            float ov  = __shfl_xor(bv, m, 64);
            int   ok  = __shfl_xor(bk, m, 64);
            float om2 = __shfl_xor(m2, m, 64);
            float nm2 = fminf(fmaxf(bv, ov), fminf(m2, om2));
            bool take = (ov < bv) || (ov == bv && ok < bk);
            bv = take ? ov : bv;
            bk = take ? ok : bk;
            m2 = nm2;
        }
        if (cmod == 0) {
            int rloc = (reg & 3) + ((reg >> 2) << 3) + (hi << 2);
            int enc  = bk;
            if (m2 - bv < GAP_THR) enc |= (int)0x80000000;
            km[(wv << 5) + rloc] = enc;
            kf[wrow0 + rloc] = enc;
        }
    }
    __syncthreads();

    // gather write
    const int half = tid >> 7, h = tid & 127;
    for (int rp = 0; rp < 64; ++rp) {
        int row = (rp << 1) + half;
        int k   = km[row] & 127;
        const float2* src = (const float2*)(cb + (size_t)k * ZD);
        float2*       dst = (float2*)(out + (size_t)(brow0 + row) * ZD);
        dst[h] = src[h];
        if (h < 127) dst[128 + h] = src[128 + h];
    }
}

// --- K2: wave-per-row exact fp32 repair, coalesced cb reads ---
__global__ __launch_bounds__(256) void repair(
    const float* __restrict__ z, const float* __restrict__ cb,
    const float* __restrict__ csq, const int* __restrict__ kf,
    float* __restrict__ out) {
    __shared__ int   kmrow[128];
    __shared__ float zsh[4][512];
    const int tid  = threadIdx.x;
    const int wv   = tid >> 6;
    const int lane = tid & 63;
    const int row0 = blockIdx.x << 7;
    if (tid < 128) kmrow[tid] = kf[row0 + tid];
    __syncthreads();
    int nflag = __syncthreads_count(tid < 128 && kmrow[tid] < 0);
    if (nflag == 0) return;

    int cnt = 0;
    for (int rl = 0; rl < 128; ++rl) {
        if (kmrow[rl] >= 0) continue;
        if ((cnt++ & 3) != wv) continue;       // wave-distributed, no block sync below
        const int row = row0 + rl;
        const float* zr = z + (size_t)row * ZD;
#pragma unroll
        for (int j = 0; j < 8; ++j) {
            int d = (j << 6) + lane;
            zsh[wv][d] = (d < ZD) ? zr[d] : 0.f;
        }
        asm volatile("s_waitcnt lgkmcnt(0)" ::: "memory");  // intra-wave LDS visibility

        float bv = 1e30f; int bk = 0;
        for (int c = 0; c < NK; ++c) {
            const float* cr = cb + (size_t)c * ZD;
            float s = 0.f;
#pragma unroll
            for (int j = 0; j < 8; ++j) {
                int d = (j << 6) + lane;
                float cv = (d < ZD) ? cr[d] : 0.f;
                s = fmaf(zsh[wv][d], cv, s);
            }
#pragma unroll
            for (int m = 1; m <= 32; m <<= 1) s += __shfl_xor(s, m, 64);
            float sc = fmaf(-2.f, s, csq[c]);
            if (sc < bv) { bv = sc; bk = c; }  // strict < keeps first index
        }
        const float2* src = (const float2*)(cb + (size_t)bk * ZD);
        float2*       dst = (float2*)(out + (size_t)row * ZD);
#pragma unroll
        for (int i = 0; i < 4; ++i) {
            int f2 = (i << 6) + lane;
            if (f2 < 255) dst[f2] = src[f2];
        }
    }
}

extern "C" void kernel_launch(void* const* d_in, const int* in_sizes, int n_in,
                              void* d_out, int out_size, void* d_ws, size_t ws_size,
                              hipStream_t stream) {
    const float* z  = (const float*)d_in[0];
    const float* cb = (const float*)d_in[1];
    float*  out  = (float*)d_out;
    float*  csq  = (float*)d_ws;
    ushort* cb16 = (ushort*)((char*)d_ws + WS_CB16_OFF);
    int*    kf   = (int*)((char*)d_ws + WS_KF_OFF);

    prep_kernel<<<NK, 256, 0, stream>>>(cb, csq, cb16);
    vq_fused<<<NB / 128, 256, 0, stream>>>(z, cb, (const uint4*)cb16, csq, kf, out);
    repair<<<NB / 128, 256, 0, stream>>>(z, cb, csq, kf, out);
}

// Round 9
// 481.636 us; speedup vs baseline: 1.8779x; 1.5000x over previous
//
#include <hip/hip_runtime.h>

#define NB 262144
#define ZD 510
#define NK 128
#define GAP_THR 0.5f
#define CHW 68                    // padded row stride in ushorts (136 B)
#define CHUNK_USH (NK * CHW)      // 8704 ushorts per chunk image
#define CHUNK_U4  (CHUNK_USH / 8) // 1088 uint4

typedef _Float16 half8 __attribute__((ext_vector_type(8)));
typedef __attribute__((ext_vector_type(16))) float f32x16;

// ws layout: [0,512) csq | [512, +139264) cb16 padded fp16 image | kf after
#define WS_CB16_OFF 512
#define WS_KF_OFF   139776

__device__ inline ushort f2h(float v) {
    return (ushort)__builtin_bit_cast(short, (_Float16)v);
}

// --- K0: csq (fp64, verified) + padded fp16 cb image (verified r7) ---
__global__ void prep_kernel(const float* __restrict__ cb, float* __restrict__ csq,
                            ushort* __restrict__ cb16) {
    const int code = blockIdx.x;
    const int tid  = threadIdx.x;
    const float* row = cb + (size_t)code * ZD;

    __shared__ double ws_red[4];
    double s = 0.0;
    for (int j = 0; j < 2; ++j) {
        int d = tid + (j << 8);
        if (d < ZD) { double v = (double)row[d]; s = fma(v, v, s); }
    }
#pragma unroll
    for (int m = 1; m <= 32; m <<= 1) s += __shfl_xor(s, m, 64);
    if ((tid & 63) == 0) ws_red[tid >> 6] = s;
    __syncthreads();
    if (tid == 0) csq[code] = (float)(ws_red[0] + ws_red[1] + ws_red[2] + ws_red[3]);

    for (int s2 = tid; s2 < 8 * CHW; s2 += 256) {
        int ch = s2 / CHW, off = s2 - ch * CHW;
        int d  = (ch << 6) + off;
        float v = (off < 64 && d < ZD) ? row[d] : 0.f;
        cb16[ch * CHUNK_USH + code * CHW + off] = f2h(v);
    }
}

// --- K1: fp16 MFMA + argmin + flag + gather; r5 skeleton, pipelined z ---
__global__ __launch_bounds__(256, 3) void vq_fused(
    const float* __restrict__ z, const float* __restrict__ cb,
    const uint4* __restrict__ cb16, const float* __restrict__ csq,
    int* __restrict__ kf, float* __restrict__ out) {
    __shared__ __align__(16) ushort cbb[2][CHUNK_USH];   // 2 x 17408 B
    __shared__ int km[128];

    const int tid   = threadIdx.x;
    const int lane  = tid & 63;
    const int wv    = tid >> 6;
    const int cmod  = lane & 31;
    const int hi    = lane >> 5;
    const int brow0 = blockIdx.x << 7;
    const int wrow0 = brow0 + (wv << 5);

    f32x16 acc[4];
#pragma unroll
    for (int cf = 0; cf < 4; ++cf)
#pragma unroll
        for (int e = 0; e < 16; ++e) acc[cf][e] = 0.f;

    const float* zrow = z + (size_t)(wrow0 + cmod) * ZD;

    float2 zr[2][16];
    // prologue: z chunk 0 (no bounds risk: d <= 62) + stage cbb[0]
#pragma unroll
    for (int t = 0; t < 4; ++t) {
        const int dbase = (t << 4) + (hi << 3);
        zr[0][t * 4 + 0] = *(const float2*)(zrow + dbase);
        zr[0][t * 4 + 1] = *(const float2*)(zrow + dbase + 2);
        zr[0][t * 4 + 2] = *(const float2*)(zrow + dbase + 4);
        zr[0][t * 4 + 3] = *(const float2*)(zrow + dbase + 6);
    }
    {
        uint4 cr0[5];
#pragma unroll
        for (int i = 0; i < 4; ++i) cr0[i] = cb16[(i << 8) + tid];
        if (tid < 64) cr0[4] = cb16[1024 + tid];
#pragma unroll
        for (int i = 0; i < 4; ++i) ((uint4*)cbb[0])[(i << 8) + tid] = cr0[i];
        if (tid < 64) ((uint4*)cbb[0])[1024 + tid] = cr0[4];
    }

#pragma unroll
    for (int c = 0; c < 8; ++c) {
        const int cur = c & 1, nxt = cur ^ 1;
        __syncthreads();                       // cbb[cur] visible; readers of cbb[nxt] done

        // convert A-fragments first (frees zr[cur] for the allocator)
        half8 afr[4];
#pragma unroll
        for (int t = 0; t < 4; ++t) {
            afr[t][0] = (_Float16)zr[cur][t * 4 + 0].x;
            afr[t][1] = (_Float16)zr[cur][t * 4 + 0].y;
            afr[t][2] = (_Float16)zr[cur][t * 4 + 1].x;
            afr[t][3] = (_Float16)zr[cur][t * 4 + 1].y;
            afr[t][4] = (_Float16)zr[cur][t * 4 + 2].x;
            afr[t][5] = (_Float16)zr[cur][t * 4 + 2].y;
            afr[t][6] = (_Float16)zr[cur][t * 4 + 3].x;
            afr[t][7] = (_Float16)zr[cur][t * 4 + 3].y;
        }

        // prefetch AFTER the barrier: cb first (ds_write waits only these),
        // then z (stays in flight under the MFMA block)
        uint4 cr[5];
        if (c < 7) {
#pragma unroll
            for (int i = 0; i < 4; ++i) cr[i] = cb16[(c + 1) * CHUNK_U4 + (i << 8) + tid];
            if (tid < 64) cr[4] = cb16[(c + 1) * CHUNK_U4 + 1024 + tid];
            const int cg = (c + 1) << 6;
#pragma unroll
            for (int t = 0; t < 4; ++t) {
                const int dbase = cg + (t << 4) + (hi << 3);
                zr[nxt][t * 4 + 0] = *(const float2*)(zrow + dbase);
                zr[nxt][t * 4 + 1] = *(const float2*)(zrow + dbase + 2);
                zr[nxt][t * 4 + 2] = *(const float2*)(zrow + dbase + 4);
                zr[nxt][t * 4 + 3] = (dbase + 6 < ZD) ? *(const float2*)(zrow + dbase + 6)
                                                      : make_float2(0.f, 0.f);
            }
        }

        // 16 MFMA on cbb[cur] (conflict-free uint2-pair B reads, proven r7)
#pragma unroll
        for (int t = 0; t < 4; ++t) {
#pragma unroll
            for (int cf = 0; cf < 4; ++cf) {
                const int bbase = (cf * 32 + cmod) * CHW + (t << 4) + (hi << 3);
                union { uint2 u2[2]; half8 h; } b;
                b.u2[0] = *(const uint2*)&cbb[cur][bbase];
                b.u2[1] = *(const uint2*)&cbb[cur][bbase + 4];
                acc[cf] = __builtin_amdgcn_mfma_f32_32x32x16_f16(afr[t], b.h, acc[cf], 0, 0, 0);
            }
        }

        // stage next cb chunk into the other buffer
        if (c < 7) {
#pragma unroll
            for (int i = 0; i < 4; ++i) ((uint4*)cbb[nxt])[(i << 8) + tid] = cr[i];
            if (tid < 64) ((uint4*)cbb[nxt])[1024 + tid] = cr[4];
        }
    }

    // ---- epilogue (byte-identical to verified rounds) ----
    float cq[4];
#pragma unroll
    for (int cf = 0; cf < 4; ++cf) cq[cf] = csq[cf * 32 + cmod];

#pragma unroll
    for (int reg = 0; reg < 16; ++reg) {
        float bv = fmaf(-2.f, acc[0][reg], cq[0]);
        int   bk = cmod;
        float m2 = 1e30f;
#pragma unroll
        for (int cf = 1; cf < 4; ++cf) {
            float v = fmaf(-2.f, acc[cf][reg], cq[cf]);
            int  kk = cf * 32 + cmod;
            if (v < bv)      { m2 = bv; bv = v; bk = kk; }
            else if (v < m2) { m2 = v; }
        }
#pragma unroll
        for (int m = 1; m <= 16; m <<= 1) {
            float ov  = __shfl_xor(bv, m, 64);
            int   ok  = __shfl_xor(bk, m, 64);
            float om2 = __shfl_xor(m2, m, 64);
            float nm2 = fminf(fmaxf(bv, ov), fminf(m2, om2));
            bool take = (ov < bv) || (ov == bv && ok < bk);
            bv = take ? ov : bv;
            bk = take ? ok : bk;
            m2 = nm2;
        }
        if (cmod == 0) {
            int rloc = (reg & 3) + ((reg >> 2) << 3) + (hi << 2);
            int enc  = bk;
            if (m2 - bv < GAP_THR) enc |= (int)0x80000000;
            km[(wv << 5) + rloc] = enc;
            kf[wrow0 + rloc] = enc;
        }
    }
    __syncthreads();

    // gather write (proven)
    const int half = tid >> 7, h = tid & 127;
    for (int rp = 0; rp < 64; ++rp) {
        int row = (rp << 1) + half;
        int k   = km[row] & 127;
        const float2* src = (const float2*)(cb + (size_t)k * ZD);
        float2*       dst = (float2*)(out + (size_t)(brow0 + row) * ZD);
        dst[h] = src[h];
        if (h < 127) dst[128 + h] = src[128 + h];
    }
}

// --- K2: wave-per-row exact fp32 repair (verified r7, byte-identical) ---
__global__ __launch_bounds__(256) void repair(
    const float* __restrict__ z, const float* __restrict__ cb,
    const float* __restrict__ csq, const int* __restrict__ kf,
    float* __restrict__ out) {
    __shared__ int   kmrow[128];
    __shared__ float zsh[4][512];
    const int tid  = threadIdx.x;
    const int wv   = tid >> 6;
    const int lane = tid & 63;
    const int row0 = blockIdx.x << 7;
    if (tid < 128) kmrow[tid] = kf[row0 + tid];
    __syncthreads();
    int nflag = __syncthreads_count(tid < 128 && kmrow[tid] < 0);
    if (nflag == 0) return;

    int cnt = 0;
    for (int rl = 0; rl < 128; ++rl) {
        if (kmrow[rl] >= 0) continue;
        if ((cnt++ & 3) != wv) continue;
        const int row = row0 + rl;
        const float* zr = z + (size_t)row * ZD;
#pragma unroll
        for (int j = 0; j < 8; ++j) {
            int d = (j << 6) + lane;
            zsh[wv][d] = (d < ZD) ? zr[d] : 0.f;
        }
        asm volatile("s_waitcnt lgkmcnt(0)" ::: "memory");

        float bv = 1e30f; int bk = 0;
        for (int c = 0; c < NK; ++c) {
            const float* cr = cb + (size_t)c * ZD;
            float s = 0.f;
#pragma unroll
            for (int j = 0; j < 8; ++j) {
                int d = (j << 6) + lane;
                float cv = (d < ZD) ? cr[d] : 0.f;
                s = fmaf(zsh[wv][d], cv, s);
            }
#pragma unroll
            for (int m = 1; m <= 32; m <<= 1) s += __shfl_xor(s, m, 64);
            float sc = fmaf(-2.f, s, csq[c]);
            if (sc < bv) { bv = sc; bk = c; }
        }
        const float2* src = (const float2*)(cb + (size_t)bk * ZD);
        float2*       dst = (float2*)(out + (size_t)row * ZD);
#pragma unroll
        for (int i = 0; i < 4; ++i) {
            int f2 = (i << 6) + lane;
            if (f2 < 255) dst[f2] = src[f2];
        }
    }
}

extern "C" void kernel_launch(void* const* d_in, const int* in_sizes, int n_in,
                              void* d_out, int out_size, void* d_ws, size_t ws_size,
                              hipStream_t stream) {
    const float* z  = (const float*)d_in[0];
    const float* cb = (const float*)d_in[1];
    float*  out  = (float*)d_out;
    float*  csq  = (float*)d_ws;
    ushort* cb16 = (ushort*)((char*)d_ws + WS_CB16_OFF);
    int*    kf   = (int*)((char*)d_ws + WS_KF_OFF);

    prep_kernel<<<NK, 256, 0, stream>>>(cb, csq, cb16);
    vq_fused<<<NB / 128, 256, 0, stream>>>(z, cb, (const uint4*)cb16, csq, kf, out);
    repair<<<NB / 128, 256, 0, stream>>>(z, cb, csq, kf, out);
}